// Round 11
// baseline (187.007 us; speedup 1.0000x reference)
//
#include <hip/hip_runtime.h>

#define NN 10000     // nodes
#define NE 640000    // edges
#define NG 64        // graphs
#define NF 128       // feature dim (both layers)
#define NC 10        // classes
#define TMR 16       // gemm row tile
#define TKC 32       // gemm k chunk
#define NB 250       // dst buckets (40 nodes each)
#define BSZ 40       // nodes per bucket
#define G1 512       // prep blocks (edge chunks)
#define GEMMB ((NN + TMR - 1) / TMR)   // 625 gemm blocks
#define ECHUNK 1250  // edges per prep block (G1*ECHUNK == NE)
#define CAP 32       // ebuf slots per (bucket, block); mean 5, P(>32) ~ 5e-12
#define CCAP 3072    // csrc entries per bucket; mean 2560 (sigma~51), +10 sigma
#define NSL 64       // outacc slices (atomic-contention spreading)
#define MAXD 192     // per-wave LDS csrc staging capacity (deg mean 64, +16 sigma)

// ---------------- ws layout (bytes) ----------------
// 0        coff    (10000 int)            40000
// 40000    deg     (10000 int)            40000
// 80000    dinv    (10000 f32)            40000
// 120000   outacc  (64 slices x 640 f32)  163840
// 283840   cntinv  (64 f32)               256
// 284160   csrc    (250*3072 ushort)      1536000  -> ends 1820160
// 1820160  bh      (250*512 int)          524288   -> ends 2344448
// 2344448  Gb      (10000*128 bf16)       2560000  -> ends 4904448   [h1, unscaled]
// 4904448  ebuf (16.4MB) | Gb2 (10000*128 bf16, h2 scaled) [ebuf dead after csr]
//
// Round-1: device atomics = ~32B RMW past XCD L2 -> reduce in registers 1st.
// Round-2: per-block fences+done-counter = L2 flush storm -> zero fences.
// Round-3/5: gatherpool was atomic-bound, NOT gather-core-bound.
// Round-6: slicing outacc (64x) fixed contention.
// Round-7: LDS-staged gather indices: -6us.
// Round-8: gemm1 fused into prep (false dinv dep broken): -6us. BEST: 159.9.
// Round-9/10 LESSONS: (a) NT stores break producer->consumer L2 reuse
// (+14us); (b) csr's strided full-region sweep reads 6.4x the occupied
// bytes cross-XCD (+17us) — the old per-cell copy already had MLP. Both
// reverted. Round-11: fuse gemm2 INTO gather1 — after gacc's xor-reduce
// every lane holds h1; apply W2 per-wave (quarter q covers k in [32q,32q+32),
// h1[k] via __shfl, W2 rows from a 128x130-padded LDS copy), write
// dinv*(h1@W2) bf16 to Gb2. Kills gemm2 launch + 10MB bufB round-trip.

__device__ __forceinline__ unsigned short f2bf(float f) {   // RNE
    unsigned int u = __float_as_uint(f);
    return (unsigned short)((u + 0x7FFF + ((u >> 16) & 1)) >> 16);
}
__device__ __forceinline__ float bf_lo(unsigned int p) {
    return __uint_as_float(p << 16);
}
__device__ __forceinline__ float bf_hi(unsigned int p) {
    return __uint_as_float(p & 0xFFFF0000u);
}

// Wave-uniform detection of int64 vs int32 index buffers.
__device__ __forceinline__ int detect64(const int* w, long span) {
    int lane = threadIdx.x & 63;
    long e = (long)lane * (span - 1) / 63;
    return (__ballot(w[2 * e + 1] != 0) == 0ULL) ? 1 : 0;
}

__device__ __forceinline__ int ld_idx(const void* p, long i, int is64) {
    return is64 ? (int)((const long long*)p)[i] : ((const int*)p)[i];
}

// Heterogeneous fused kernel. Blocks [0, G1): edge hist+scatter; block 0
// zeroes sliced outacc, block 8 computes cntinv. Blocks [G1, G1+GEMMB):
// gemm1 tiles Y = bf16(X @ W1), UNSCALED (no dinv dependency).
__global__ __launch_bounds__(256) void k_prepgemm(const void* __restrict__ ei,
                                                  const void* __restrict__ batch,
                                                  int* __restrict__ bh,
                                                  int* __restrict__ ebuf,
                                                  float* __restrict__ outacc,
                                                  float* __restrict__ cntinv,
                                                  const float* __restrict__ X,
                                                  const float* __restrict__ W,
                                                  unsigned short* __restrict__ Y) {
    __shared__ int hist[256];
    __shared__ int cur[256];
    __shared__ float sX[TKC * 20];       // [k][m] stride 20
    __shared__ float sW[32 * 132];
    int tid = threadIdx.x;

    if (blockIdx.x >= G1) {              // ---- gemm1 tile (unscaled) ----
        int m0 = (int)(blockIdx.x - G1) * TMR;
        int rg = tid & 7;                // rows rg*2, rg*2+1
        int cg = tid >> 3;               // cols cg*4 .. cg*4+3
        float acc[2][4] = {{0.f}};
        for (int kc = 0; kc < NF / TKC; ++kc) {
            int k0 = kc * TKC;
            if (tid < 128) {
                int row = tid >> 3, kq = tid & 7;
                int mm = m0 + row; if (mm > NN - 1) mm = NN - 1;
                float4 v = *(const float4*)(X + (size_t)mm * NF + k0 + kq * 4);
                sX[(kq * 4 + 0) * 20 + row] = v.x;
                sX[(kq * 4 + 1) * 20 + row] = v.y;
                sX[(kq * 4 + 2) * 20 + row] = v.z;
                sX[(kq * 4 + 3) * 20 + row] = v.w;
            }
#pragma unroll
            for (int j = 0; j < 4; ++j) {
                int idx = tid + 256 * j;
                int k = idx >> 5, cq = idx & 31;
                float4 v = *(const float4*)(W + (size_t)(k0 + k) * NF + cq * 4);
                *(float4*)(sW + cq * 132 + k * 4) = v;
            }
            __syncthreads();
#pragma unroll 8
            for (int k = 0; k < TKC; ++k) {
                float2 xf = *(const float2*)(sX + k * 20 + rg * 2);
                float4 wf = *(const float4*)(sW + cg * 132 + k * 4);
                acc[0][0] = fmaf(xf.x, wf.x, acc[0][0]);
                acc[0][1] = fmaf(xf.x, wf.y, acc[0][1]);
                acc[0][2] = fmaf(xf.x, wf.z, acc[0][2]);
                acc[0][3] = fmaf(xf.x, wf.w, acc[0][3]);
                acc[1][0] = fmaf(xf.y, wf.x, acc[1][0]);
                acc[1][1] = fmaf(xf.y, wf.y, acc[1][1]);
                acc[1][2] = fmaf(xf.y, wf.z, acc[1][2]);
                acc[1][3] = fmaf(xf.y, wf.w, acc[1][3]);
            }
            __syncthreads();
        }
#pragma unroll
        for (int r = 0; r < 2; ++r) {
            int m = m0 + rg * 2 + r;
            if (m < NN) {
                ushort4 h;
                h.x = f2bf(acc[r][0]);
                h.y = f2bf(acc[r][1]);
                h.z = f2bf(acc[r][2]);
                h.w = f2bf(acc[r][3]);
                *(ushort4*)(Y + (size_t)m * NF + cg * 4) = h;
            }
        }
        return;
    }

    // ---- prep (edge hist + scatter) ----
    int is64 = detect64((const int*)ei, NE);
    hist[tid] = 0;
    __syncthreads();
    if (blockIdx.x == 0) {
        for (int i = tid; i < NSL * NG * NC; i += 256) outacc[i] = 0.f;
    }
    if (blockIdx.x == 8 && tid < NG) {
        int isb = detect64((const int*)batch, NN / 2);
        int lo0 = 0, hi0 = NN;
        while (lo0 < hi0) {
            int m = (lo0 + hi0) >> 1;
            if (ld_idx(batch, m, isb) < tid) lo0 = m + 1; else hi0 = m;
        }
        int lo1 = lo0, hi1 = NN;
        while (lo1 < hi1) {
            int m = (lo1 + hi1) >> 1;
            if (ld_idx(batch, m, isb) < tid + 1) lo1 = m + 1; else hi1 = m;
        }
        cntinv[tid] = 1.0f / fmaxf((float)(lo1 - lo0), 1.0f);
    }
    int e0 = blockIdx.x * ECHUNK;
    int dstv[5], srcv[5];
#pragma unroll
    for (int i = 0; i < 5; ++i) {
        int r = tid + i * 256;
        if (r < ECHUNK) {
            long e = (long)e0 + r;
            dstv[i] = ld_idx(ei, (long)NE + e, is64);
            srcv[i] = ld_idx(ei, e, is64);
            atomicAdd(&hist[dstv[i] / BSZ], 1);
        } else {
            dstv[i] = -1; srcv[i] = 0;
        }
    }
    __syncthreads();
    if (tid < NB) {
        bh[tid * G1 + blockIdx.x] = min(hist[tid], CAP);
        cur[tid] = (tid * G1 + blockIdx.x) * CAP;
    }
    __syncthreads();
#pragma unroll
    for (int i = 0; i < 5; ++i) {
        if (tid + i * 256 < ECHUNK) {
            int dst = dstv[i], src = srcv[i];
            int b = dst / BSZ;
            int p = atomicAdd(&cur[b], 1);
            int lim = (b * G1 + blockIdx.x) * CAP + CAP;
            if (p < lim) ebuf[p] = ((dst - b * BSZ) << 14) | src;
        }
    }
}

// One block per bucket (round-8 verified form: per-cell copy, which already
// has MLP across the 128 independent cells each thread handles).
__global__ __launch_bounds__(256) void k_csr(const int* __restrict__ ebuf,
                                             const int* __restrict__ bh,
                                             int* __restrict__ coff,
                                             int* __restrict__ deg,
                                             float* __restrict__ dinv,
                                             unsigned short* __restrict__ csrc) {
    __shared__ int scnt[G1];
    __shared__ int cbase[G1];
    __shared__ int wsum[4];
    __shared__ int eb[CCAP];
    __shared__ int dcount[BSZ];
    __shared__ int cur[BSZ];
    int b = blockIdx.x, tid = threadIdx.x;
    int lane = tid & 63, wv = tid >> 6;
    for (int i = tid; i < G1; i += 256) scnt[i] = bh[b * G1 + i];
    if (tid < BSZ) dcount[tid] = 0;
    __syncthreads();
    int v0 = scnt[2 * tid], v1 = scnt[2 * tid + 1];
    int lsum = v0 + v1;
    int pref = lsum;
    for (int o = 1; o < 64; o <<= 1) {
        int t = __shfl_up(pref, o, 64);
        if (lane >= o) pref += t;
    }
    if (lane == 63) wsum[wv] = pref;
    __syncthreads();
    int off = 0;
#pragma unroll
    for (int j = 0; j < 4; ++j) if (j < wv) off += wsum[j];
    int ex = pref - lsum + off;
    cbase[2 * tid] = ex;
    cbase[2 * tid + 1] = ex + v0;
    int tot = wsum[0] + wsum[1] + wsum[2] + wsum[3];
    if (tot > CCAP) tot = CCAP;
    __syncthreads();
#pragma unroll
    for (int cp = 0; cp < 2; ++cp) {     // copy cells 2t, 2t+1 into LDS
        int cell = 2 * tid + cp;
        int c = scnt[cell], lb = cbase[cell];
        int gb = (b * G1 + cell) * CAP;
        if (lb + c > CCAP) c = max(0, CCAP - lb);
        for (int i = 0; i < c; ++i) eb[lb + i] = ebuf[gb + i];
    }
    __syncthreads();
    for (int i = tid; i < tot; i += 256)
        atomicAdd(&dcount[eb[i] >> 14], 1);
    __syncthreads();
    if (tid < 64) {
        int d = (tid < BSZ) ? dcount[tid] : 0;
        int pr = d;
        for (int o = 1; o < 64; o <<= 1) {
            int t = __shfl_up(pr, o, 64);
            if (tid >= o) pr += t;
        }
        if (tid < BSZ) {
            int st = pr - d;
            cur[tid] = b * CCAP + st;
            coff[b * BSZ + tid] = b * CCAP + st;
            deg[b * BSZ + tid] = d;
            dinv[b * BSZ + tid] = rsqrtf((float)d + 1.0f);
        }
    }
    __syncthreads();
    for (int i = tid; i < tot; i += 256) {
        int pk = eb[i];
        int p = atomicAdd(&cur[pk >> 14], 1);
        csrc[p] = (unsigned short)(pk & 16383);
    }
}

// Gather core, LDS-staged indices (+ per-edge dinv when G rows unscaled).
template <int EDGE_SCALE>
__device__ __forceinline__ void gacc_node(const unsigned short* __restrict__ G,
                                          const unsigned short* __restrict__ csrc,
                                          const float* __restrict__ dv,
                                          unsigned short* ls, float* lsd,
                                          int beg, int end, int q, int f, int lane,
                                          float a[8]) {
    int dg = end - beg;
    int nst = min(dg, MAXD);
    for (int i = lane; i < nst; i += 64) {
        unsigned short s = csrc[beg + i];
        ls[i] = s;
        if (EDGE_SCALE) lsd[i] = dv[s];
    }
    int vi = q;
    int nfull = nst & ~31;
    for (; vi < nfull; vi += 32) {
        int s[8]; float d[8];
#pragma unroll
        for (int j = 0; j < 8; ++j) {
            s[j] = ls[vi + 4 * j];
            d[j] = EDGE_SCALE ? lsd[vi + 4 * j] : 1.f;
        }
        uint4 p[8];
#pragma unroll
        for (int j = 0; j < 8; ++j)
            p[j] = ((const uint4*)(G + (size_t)s[j] * NF))[f];
#pragma unroll
        for (int j = 0; j < 8; ++j) {
            if (EDGE_SCALE) {
                a[0] = fmaf(d[j], bf_lo(p[j].x), a[0]); a[1] = fmaf(d[j], bf_hi(p[j].x), a[1]);
                a[2] = fmaf(d[j], bf_lo(p[j].y), a[2]); a[3] = fmaf(d[j], bf_hi(p[j].y), a[3]);
                a[4] = fmaf(d[j], bf_lo(p[j].z), a[4]); a[5] = fmaf(d[j], bf_hi(p[j].z), a[5]);
                a[6] = fmaf(d[j], bf_lo(p[j].w), a[6]); a[7] = fmaf(d[j], bf_hi(p[j].w), a[7]);
            } else {
                a[0] += bf_lo(p[j].x); a[1] += bf_hi(p[j].x);
                a[2] += bf_lo(p[j].y); a[3] += bf_hi(p[j].y);
                a[4] += bf_lo(p[j].z); a[5] += bf_hi(p[j].z);
                a[6] += bf_lo(p[j].w); a[7] += bf_hi(p[j].w);
            }
        }
    }
    int nfull16 = nst & ~15;
    for (; vi < nfull16; vi += 16) {
        int s[4]; float d[4];
#pragma unroll
        for (int j = 0; j < 4; ++j) {
            s[j] = ls[vi + 4 * j];
            d[j] = EDGE_SCALE ? lsd[vi + 4 * j] : 1.f;
        }
        uint4 p[4];
#pragma unroll
        for (int j = 0; j < 4; ++j)
            p[j] = ((const uint4*)(G + (size_t)s[j] * NF))[f];
#pragma unroll
        for (int j = 0; j < 4; ++j) {
            if (EDGE_SCALE) {
                a[0] = fmaf(d[j], bf_lo(p[j].x), a[0]); a[1] = fmaf(d[j], bf_hi(p[j].x), a[1]);
                a[2] = fmaf(d[j], bf_lo(p[j].y), a[2]); a[3] = fmaf(d[j], bf_hi(p[j].y), a[3]);
                a[4] = fmaf(d[j], bf_lo(p[j].z), a[4]); a[5] = fmaf(d[j], bf_hi(p[j].z), a[5]);
                a[6] = fmaf(d[j], bf_lo(p[j].w), a[6]); a[7] = fmaf(d[j], bf_hi(p[j].w), a[7]);
            } else {
                a[0] += bf_lo(p[j].x); a[1] += bf_hi(p[j].x);
                a[2] += bf_lo(p[j].y); a[3] += bf_hi(p[j].y);
                a[4] += bf_lo(p[j].z); a[5] += bf_hi(p[j].z);
                a[6] += bf_lo(p[j].w); a[7] += bf_hi(p[j].w);
            }
        }
    }
    int npad = (nst + 3) & ~3;
    for (; vi < npad; vi += 4) {         // predicated tail, uniform trips
        int ii = min(vi, nst - 1);
        int s = ls[ii];
        float d = EDGE_SCALE ? lsd[ii] : 1.f;
        uint4 p = ((const uint4*)(G + (size_t)s * NF))[f];
        if (vi < nst) {
            if (EDGE_SCALE) {
                a[0] = fmaf(d, bf_lo(p.x), a[0]); a[1] = fmaf(d, bf_hi(p.x), a[1]);
                a[2] = fmaf(d, bf_lo(p.y), a[2]); a[3] = fmaf(d, bf_hi(p.y), a[3]);
                a[4] = fmaf(d, bf_lo(p.z), a[4]); a[5] = fmaf(d, bf_hi(p.z), a[5]);
                a[6] = fmaf(d, bf_lo(p.w), a[6]); a[7] = fmaf(d, bf_hi(p.w), a[7]);
            } else {
                a[0] += bf_lo(p.x); a[1] += bf_hi(p.x);
                a[2] += bf_lo(p.y); a[3] += bf_hi(p.y);
                a[4] += bf_lo(p.z); a[5] += bf_hi(p.z);
                a[6] += bf_lo(p.w); a[7] += bf_hi(p.w);
            }
        }
    }
    for (int e2 = beg + MAXD + q; e2 < end; e2 += 4) {  // deg>MAXD fallback
        int s = csrc[e2];
        float d = EDGE_SCALE ? dv[s] : 1.f;
        uint4 p = ((const uint4*)(G + (size_t)s * NF))[f];
        if (EDGE_SCALE) {
            a[0] = fmaf(d, bf_lo(p.x), a[0]); a[1] = fmaf(d, bf_hi(p.x), a[1]);
            a[2] = fmaf(d, bf_lo(p.y), a[2]); a[3] = fmaf(d, bf_hi(p.y), a[3]);
            a[4] = fmaf(d, bf_lo(p.z), a[4]); a[5] = fmaf(d, bf_hi(p.z), a[5]);
            a[6] = fmaf(d, bf_lo(p.w), a[6]); a[7] = fmaf(d, bf_hi(p.w), a[7]);
        } else {
            a[0] += bf_lo(p.x); a[1] += bf_hi(p.x);
            a[2] += bf_lo(p.y); a[3] += bf_hi(p.y);
            a[4] += bf_lo(p.z); a[5] += bf_hi(p.z);
            a[6] += bf_lo(p.w); a[7] += bf_hi(p.w);
        }
    }
#pragma unroll
    for (int j = 0; j < 8; ++j) a[j] += __shfl_xor(a[j], 16);
#pragma unroll
    for (int j = 0; j < 8; ++j) a[j] += __shfl_xor(a[j], 32);
}

// FUSED layer-1 gather + gemm2. 512 threads = 8 waves, one node per wave
// (1250 blocks x 8 = 10000 exactly). After gacc's xor-reduce every lane
// holds h1 (lane f owns features f*8..f*8+7, replicated across quarters).
// Per-wave gemm2: quarter q covers k in [32q, 32q+32); h1[k] comes from
// lane 20q+(kk>>3) via __shfl (h[kk&7] there == h1[32q+kk]); W2 row k from
// the 128x130-padded LDS copy. Quarters hold disjoint-k partials ->
// xor16/32 reduce -> q==0 writes bf16 dinv*(h1@W2) to Y (= Gb2; Gb must
// not be written in place while other waves still gather from it).
__global__ __launch_bounds__(512, 4) void k_gatherg2(const unsigned short* __restrict__ G,
                                                     const int* __restrict__ off,
                                                     const int* __restrict__ dg,
                                                     const unsigned short* __restrict__ csrc,
                                                     const float* __restrict__ dinv,
                                                     const float* __restrict__ bias,
                                                     const float* __restrict__ W2,
                                                     unsigned short* __restrict__ Y) {
    __shared__ float sW2[NF * 130];          // 66.6 KB, +2 pad breaks bank cycle
    __shared__ unsigned short lsbuf[8][MAXD];
    __shared__ float lsdbuf[8][MAXD];
    int tid = threadIdx.x;
#pragma unroll
    for (int it = 0; it < 8; ++it) {         // stage W2 (512 thr x 8 float4)
        int m = (tid + it * 512) * 4;        // flat idx; row-contained
        int k = m >> 7, c = m & 127;
        float4 v = *(const float4*)(W2 + m);
        *(float4*)(&sW2[k * 130 + c]) = v;
    }
    int wid = tid >> 6, lane = tid & 63;
    int q = lane >> 4, f = lane & 15;
    int n = blockIdx.x * 8 + wid;            // exactly NN
    int beg = off[n], end = beg + dg[n];
    float din = dinv[n];
    float a[8] = {0.f, 0.f, 0.f, 0.f, 0.f, 0.f, 0.f, 0.f};
    __syncthreads();                         // sW2 ready; only block-wide sync
    gacc_node<1>(G, csrc, dinv, lsbuf[wid], lsdbuf[wid], beg, end, q, f, lane, a);
    // layer-1 epilogue on ALL lanes (h1 needed everywhere for the gemm)
    uint4 sp = ((const uint4*)(G + (size_t)n * NF))[f];
    float4 b0 = ((const float4*)bias)[2 * f];
    float4 b1 = ((const float4*)bias)[2 * f + 1];
    float h[8];
    h[0] = fmaxf(fmaf(din, fmaf(din, bf_lo(sp.x), a[0]), b0.x), 0.f);
    h[1] = fmaxf(fmaf(din, fmaf(din, bf_hi(sp.x), a[1]), b0.y), 0.f);
    h[2] = fmaxf(fmaf(din, fmaf(din, bf_lo(sp.y), a[2]), b0.z), 0.f);
    h[3] = fmaxf(fmaf(din, fmaf(din, bf_hi(sp.y), a[3]), b0.w), 0.f);
    h[4] = fmaxf(fmaf(din, fmaf(din, bf_lo(sp.z), a[4]), b1.x), 0.f);
    h[5] = fmaxf(fmaf(din, fmaf(din, bf_hi(sp.z), a[5]), b1.y), 0.f);
    h[6] = fmaxf(fmaf(din, fmaf(din, bf_lo(sp.w), a[6]), b1.z), 0.f);
    h[7] = fmaxf(fmaf(din, fmaf(din, bf_hi(sp.w), a[7]), b1.w), 0.f);
    float o[8] = {0.f, 0.f, 0.f, 0.f, 0.f, 0.f, 0.f, 0.f};
#pragma unroll
    for (int kk = 0; kk < 32; ++kk) {        // quarter-local k range
        int k = q * 32 + kk;
        float hh = __shfl(h[kk & 7], 20 * q + (kk >> 3), 64);
        const float* wr = &sW2[k * 130 + f * 8];
        float4 w0 = *(const float4*)(wr);
        float4 w1 = *(const float4*)(wr + 4);
        o[0] = fmaf(hh, w0.x, o[0]); o[1] = fmaf(hh, w0.y, o[1]);
        o[2] = fmaf(hh, w0.z, o[2]); o[3] = fmaf(hh, w0.w, o[3]);
        o[4] = fmaf(hh, w1.x, o[4]); o[5] = fmaf(hh, w1.y, o[5]);
        o[6] = fmaf(hh, w1.z, o[6]); o[7] = fmaf(hh, w1.w, o[7]);
    }
#pragma unroll
    for (int j = 0; j < 8; ++j) {            // combine disjoint-k quarters
        o[j] += __shfl_xor(o[j], 16);
        o[j] += __shfl_xor(o[j], 32);
    }
    if (q == 0) {                            // write h2 = dinv * (h1 @ W2)
        ushort4 y0, y1;
        y0.x = f2bf(o[0] * din); y0.y = f2bf(o[1] * din);
        y0.z = f2bf(o[2] * din); y0.w = f2bf(o[3] * din);
        y1.x = f2bf(o[4] * din); y1.y = f2bf(o[5] * din);
        y1.z = f2bf(o[6] * din); y1.w = f2bf(o[7] * din);
        *(ushort4*)(Y + (size_t)n * NF + f * 8) = y0;
        *(ushort4*)(Y + (size_t)n * NF + f * 8 + 4) = y1;
    }
}

// Layer-2 gather fused with mean-pool + final linear (sliced atomics;
// G rows pre-scaled -> EDGE_SCALE=0). Unchanged from round 8.
__global__ __launch_bounds__(256, 4) void k_gatherpool(const unsigned short* __restrict__ G,
                                                       const int* __restrict__ off,
                                                       const int* __restrict__ dg,
                                                       const unsigned short* __restrict__ csrc,
                                                       const float* __restrict__ dinv,
                                                       const float* __restrict__ bias,
                                                       const void* __restrict__ batch,
                                                       const float* __restrict__ Wl,
                                                       const float* __restrict__ cntinv,
                                                       float* __restrict__ outacc) {
    __shared__ float sWl2[8 * NC * 16];  // [j][c][f], conflict-free reads
    __shared__ unsigned short lsbuf[4][MAXD];
    int tid = threadIdx.x;
    for (int i = tid; i < 8 * NC * 16; i += 256) {
        int j = i / (NC * 16);
        int r = i - j * (NC * 16);
        int c = r >> 4, f0 = r & 15;
        sWl2[i] = Wl[(f0 * 8 + j) * NC + c];
    }
    int isb64 = detect64((const int*)batch, NN / 2);
    int wid = tid >> 6, lane = tid & 63;
    int q = lane >> 4, f = lane & 15;
    int n = blockIdx.x * 4 + wid;        // grid is exactly NN/4 -> always valid
    int beg = off[n], end = beg + dg[n];
    float din = dinv[n];
    float a[8] = {0.f, 0.f, 0.f, 0.f, 0.f, 0.f, 0.f, 0.f};
    __syncthreads();                     // sWl2 ready; last block-wide sync
    gacc_node<0>(G, csrc, dinv, lsbuf[wid], (float*)nullptr, beg, end, q, f, lane, a);
    int g = ld_idx(batch, n, isb64);
    uint4 sp = ((const uint4*)(G + (size_t)n * NF))[f];
    float4 b0 = ((const float4*)bias)[2 * f];
    float4 b1 = ((const float4*)bias)[2 * f + 1];
    float h[8];
    h[0] = fmaxf(fmaf(din, a[0] + bf_lo(sp.x), b0.x), 0.f);
    h[1] = fmaxf(fmaf(din, a[1] + bf_hi(sp.x), b0.y), 0.f);
    h[2] = fmaxf(fmaf(din, a[2] + bf_lo(sp.y), b0.z), 0.f);
    h[3] = fmaxf(fmaf(din, a[3] + bf_hi(sp.y), b0.w), 0.f);
    h[4] = fmaxf(fmaf(din, a[4] + bf_lo(sp.z), b1.x), 0.f);
    h[5] = fmaxf(fmaf(din, a[5] + bf_hi(sp.z), b1.y), 0.f);
    h[6] = fmaxf(fmaf(din, a[6] + bf_lo(sp.w), b1.z), 0.f);
    h[7] = fmaxf(fmaf(din, a[7] + bf_hi(sp.w), b1.w), 0.f);
    float p[NC];
#pragma unroll
    for (int c = 0; c < NC; ++c) p[c] = 0.f;
#pragma unroll
    for (int j = 0; j < 8; ++j) {
        const float* wrow = sWl2 + j * (NC * 16) + f;  // [c*16 + f]
#pragma unroll
        for (int c = 0; c < NC; ++c) p[c] = fmaf(h[j], wrow[c * 16], p[c]);
    }
#pragma unroll
    for (int c = 0; c < NC; ++c) {       // reduce over f (bits 0..3)
        p[c] += __shfl_xor(p[c], 1);
        p[c] += __shfl_xor(p[c], 2);
        p[c] += __shfl_xor(p[c], 4);
        p[c] += __shfl_xor(p[c], 8);
    }
    if (lane == 0) {                     // 10 atomics into this block's slice
        float ci = cntinv[g];
        float* dst = outacc + (size_t)(blockIdx.x & (NSL - 1)) * NG * NC + g * NC;
#pragma unroll
        for (int c = 0; c < NC; ++c) atomicAdd(dst + c, p[c] * ci);
    }
}

// Epilogue: out = sum_slices(outacc) + bl (stream-order visibility).
__global__ __launch_bounds__(256) void k_fin(const float* __restrict__ outacc,
                                             const float* __restrict__ bl,
                                             float* __restrict__ out) {
    int tid = threadIdx.x;
    for (int i = tid; i < NG * NC; i += 256) {
        float s = 0.f;
#pragma unroll 8
        for (int sl = 0; sl < NSL; ++sl) s += outacc[(size_t)sl * NG * NC + i];
        out[i] = s + bl[i % NC];
    }
}

extern "C" void kernel_launch(void* const* d_in, const int* in_sizes, int n_in,
                              void* d_out, int out_size, void* d_ws, size_t ws_size,
                              hipStream_t stream) {
    const float* x  = (const float*)d_in[0];
    const void*  ei = d_in[1];
    const void*  bt = d_in[2];
    const float* W1 = (const float*)d_in[3];
    const float* b1 = (const float*)d_in[4];
    const float* W2 = (const float*)d_in[5];
    const float* b2 = (const float*)d_in[6];
    const float* Wl = (const float*)d_in[7];
    const float* bl = (const float*)d_in[8];

    char* ws = (char*)d_ws;
    int*            coff   = (int*)(ws + 0);
    int*            deg    = (int*)(ws + 40000);
    float*          dinv   = (float*)(ws + 80000);
    float*          outacc = (float*)(ws + 120000);   // 64 slices x 640 f32
    float*          cntinv = (float*)(ws + 283840);
    unsigned short* csrc   = (unsigned short*)(ws + 284160);
    int*            bh     = (int*)(ws + 1820160);
    unsigned short* Gb     = (unsigned short*)(ws + 2344448); // h1 (unscaled)
    int*            ebuf   = (int*)(ws + 4904448);
    unsigned short* Gb2    = (unsigned short*)(ws + 4904448); // h2; aliases ebuf (dead after csr)

    k_prepgemm<<<G1 + GEMMB, 256, 0, stream>>>(ei, bt, bh, ebuf, outacc, cntinv,
                                               x, W1, Gb);
    k_csr <<<NB, 256, 0, stream>>>(ebuf, bh, coff, deg, dinv, csrc);

    k_gatherg2<<<NN / 8, 512, 0, stream>>>(Gb, coff, deg, csrc, dinv, b1, W2, Gb2);
    k_gatherpool<<<(NN + 3) / 4, 256, 0, stream>>>(Gb2, coff, deg, csrc, dinv, b2,
                                                   bt, Wl, cntinv, outacc);
    k_fin<<<1, 256, 0, stream>>>(outacc, bl, (float*)d_out);
}

// Round 12
// 157.349 us; speedup vs baseline: 1.1885x; 1.1885x over previous
//
#include <hip/hip_runtime.h>

#define NN 10000     // nodes
#define NE 640000    // edges
#define NG 64        // graphs
#define NF 128       // feature dim (both layers)
#define NC 10        // classes
#define TMR 16       // gemm row tile
#define TKC 32       // gemm k chunk
#define NB 250       // dst buckets (40 nodes each)
#define BSZ 40       // nodes per bucket
#define G1 512       // prep blocks (edge chunks)
#define GEMMB ((NN + TMR - 1) / TMR)   // 625 gemm blocks
#define ECHUNK 1250  // edges per prep block (G1*ECHUNK == NE)
#define CAP 32       // ebuf slots per (bucket, block); mean 5, P(>32) ~ 5e-12
#define CCAP 3072    // csrc entries per bucket; mean 2560 (sigma~51), +10 sigma
#define NSL 64       // outacc slices (atomic-contention spreading)
#define MAXD 192     // per-wave LDS csrc staging capacity (deg mean 64, +16 sigma)

// ---------------- ws layout (bytes) ----------------
// 0        coff    (10000 int)            40000
// 40000    deg     (10000 int)            40000
// 80000    dinv    (10000 f32)            40000
// 120000   outacc  (64 slices x 640 f32)  163840
// 283840   cntinv  (64 f32)               256
// 284160   csrc    (250*3072 ushort)      1536000  -> ends 1820160
// 1820160  bh      (250*512 int)          524288   -> ends 2344448
// 2344448  Gb      (10000*128 bf16)       2560000  -> ends 4904448
// 4904448  ebuf    (128000*32 int, 16.4MB) | bufB (10000*128 f32) [ebuf dead after csr]
//
// EXACT ROUND-8 REVERT (verified 159.9us — session best).
// Round-1: device atomics = ~32B RMW past XCD L2 -> reduce in registers 1st.
// Round-2: per-block fences+done-counter = L2 flush storm -> zero fences.
// Round-3/5: gatherpool was atomic-bound, NOT gather-core-bound.
// Round-6: slicing outacc (64x) fixed contention.
// Round-7: LDS-staged gather indices: -6us.
// Round-8: gemm1 fused into prep (false dinv dep broken): -6us. BEST.
// Round-9: NT stores broke producer->consumer L2 reuse (+14us). Reverted.
// Round-10: csr strided full-region sweep reads 6.4x bytes cross-XCD
//           (+17us); per-cell copy already had MLP. Reverted.
// Round-11: gemm2-into-gather fusion: 60us fused kernel (31% occupancy,
//           8-wave block coupling, 4-way sW2 bank conflicts, serial shfl
//           gemm tail) > the ~30us it replaced. Reverted.

__device__ __forceinline__ unsigned short f2bf(float f) {   // RNE
    unsigned int u = __float_as_uint(f);
    return (unsigned short)((u + 0x7FFF + ((u >> 16) & 1)) >> 16);
}
__device__ __forceinline__ float bf_lo(unsigned int p) {
    return __uint_as_float(p << 16);
}
__device__ __forceinline__ float bf_hi(unsigned int p) {
    return __uint_as_float(p & 0xFFFF0000u);
}

// Wave-uniform detection of int64 vs int32 index buffers.
__device__ __forceinline__ int detect64(const int* w, long span) {
    int lane = threadIdx.x & 63;
    long e = (long)lane * (span - 1) / 63;
    return (__ballot(w[2 * e + 1] != 0) == 0ULL) ? 1 : 0;
}

__device__ __forceinline__ int ld_idx(const void* p, long i, int is64) {
    return is64 ? (int)((const long long*)p)[i] : ((const int*)p)[i];
}

// Heterogeneous fused kernel. Blocks [0, G1): edge hist+scatter; block 0
// zeroes sliced outacc, block 8 computes cntinv. Blocks [G1, G1+GEMMB):
// gemm1 tiles Y = bf16(X @ W1), UNSCALED (no dinv dependency).
__global__ __launch_bounds__(256) void k_prepgemm(const void* __restrict__ ei,
                                                  const void* __restrict__ batch,
                                                  int* __restrict__ bh,
                                                  int* __restrict__ ebuf,
                                                  float* __restrict__ outacc,
                                                  float* __restrict__ cntinv,
                                                  const float* __restrict__ X,
                                                  const float* __restrict__ W,
                                                  unsigned short* __restrict__ Y) {
    __shared__ int hist[256];
    __shared__ int cur[256];
    __shared__ float sX[TKC * 20];       // [k][m] stride 20
    __shared__ float sW[32 * 132];
    int tid = threadIdx.x;

    if (blockIdx.x >= G1) {              // ---- gemm1 tile (unscaled) ----
        int m0 = (int)(blockIdx.x - G1) * TMR;
        int rg = tid & 7;                // rows rg*2, rg*2+1
        int cg = tid >> 3;               // cols cg*4 .. cg*4+3
        float acc[2][4] = {{0.f}};
        for (int kc = 0; kc < NF / TKC; ++kc) {
            int k0 = kc * TKC;
            if (tid < 128) {
                int row = tid >> 3, kq = tid & 7;
                int mm = m0 + row; if (mm > NN - 1) mm = NN - 1;
                float4 v = *(const float4*)(X + (size_t)mm * NF + k0 + kq * 4);
                sX[(kq * 4 + 0) * 20 + row] = v.x;
                sX[(kq * 4 + 1) * 20 + row] = v.y;
                sX[(kq * 4 + 2) * 20 + row] = v.z;
                sX[(kq * 4 + 3) * 20 + row] = v.w;
            }
#pragma unroll
            for (int j = 0; j < 4; ++j) {
                int idx = tid + 256 * j;
                int k = idx >> 5, cq = idx & 31;
                float4 v = *(const float4*)(W + (size_t)(k0 + k) * NF + cq * 4);
                *(float4*)(sW + cq * 132 + k * 4) = v;
            }
            __syncthreads();
#pragma unroll 8
            for (int k = 0; k < TKC; ++k) {
                float2 xf = *(const float2*)(sX + k * 20 + rg * 2);
                float4 wf = *(const float4*)(sW + cg * 132 + k * 4);
                acc[0][0] = fmaf(xf.x, wf.x, acc[0][0]);
                acc[0][1] = fmaf(xf.x, wf.y, acc[0][1]);
                acc[0][2] = fmaf(xf.x, wf.z, acc[0][2]);
                acc[0][3] = fmaf(xf.x, wf.w, acc[0][3]);
                acc[1][0] = fmaf(xf.y, wf.x, acc[1][0]);
                acc[1][1] = fmaf(xf.y, wf.y, acc[1][1]);
                acc[1][2] = fmaf(xf.y, wf.z, acc[1][2]);
                acc[1][3] = fmaf(xf.y, wf.w, acc[1][3]);
            }
            __syncthreads();
        }
#pragma unroll
        for (int r = 0; r < 2; ++r) {
            int m = m0 + rg * 2 + r;
            if (m < NN) {
                ushort4 h;
                h.x = f2bf(acc[r][0]);
                h.y = f2bf(acc[r][1]);
                h.z = f2bf(acc[r][2]);
                h.w = f2bf(acc[r][3]);
                *(ushort4*)(Y + (size_t)m * NF + cg * 4) = h;
            }
        }
        return;
    }

    // ---- prep (edge hist + scatter) ----
    int is64 = detect64((const int*)ei, NE);
    hist[tid] = 0;
    __syncthreads();
    if (blockIdx.x == 0) {
        for (int i = tid; i < NSL * NG * NC; i += 256) outacc[i] = 0.f;
    }
    if (blockIdx.x == 8 && tid < NG) {
        int isb = detect64((const int*)batch, NN / 2);
        int lo0 = 0, hi0 = NN;
        while (lo0 < hi0) {
            int m = (lo0 + hi0) >> 1;
            if (ld_idx(batch, m, isb) < tid) lo0 = m + 1; else hi0 = m;
        }
        int lo1 = lo0, hi1 = NN;
        while (lo1 < hi1) {
            int m = (lo1 + hi1) >> 1;
            if (ld_idx(batch, m, isb) < tid + 1) lo1 = m + 1; else hi1 = m;
        }
        cntinv[tid] = 1.0f / fmaxf((float)(lo1 - lo0), 1.0f);
    }
    int e0 = blockIdx.x * ECHUNK;
    int dstv[5], srcv[5];
#pragma unroll
    for (int i = 0; i < 5; ++i) {
        int r = tid + i * 256;
        if (r < ECHUNK) {
            long e = (long)e0 + r;
            dstv[i] = ld_idx(ei, (long)NE + e, is64);
            srcv[i] = ld_idx(ei, e, is64);
            atomicAdd(&hist[dstv[i] / BSZ], 1);
        } else {
            dstv[i] = -1; srcv[i] = 0;
        }
    }
    __syncthreads();
    if (tid < NB) {
        bh[tid * G1 + blockIdx.x] = min(hist[tid], CAP);
        cur[tid] = (tid * G1 + blockIdx.x) * CAP;
    }
    __syncthreads();
#pragma unroll
    for (int i = 0; i < 5; ++i) {
        if (tid + i * 256 < ECHUNK) {
            int dst = dstv[i], src = srcv[i];
            int b = dst / BSZ;
            int p = atomicAdd(&cur[b], 1);
            int lim = (b * G1 + blockIdx.x) * CAP + CAP;
            if (p < lim) ebuf[p] = ((dst - b * BSZ) << 14) | src;
        }
    }
}

// One block per bucket (round-8 verified form: per-cell copy, which already
// has MLP across the independent cells each thread handles).
__global__ __launch_bounds__(256) void k_csr(const int* __restrict__ ebuf,
                                             const int* __restrict__ bh,
                                             int* __restrict__ coff,
                                             int* __restrict__ deg,
                                             float* __restrict__ dinv,
                                             unsigned short* __restrict__ csrc) {
    __shared__ int scnt[G1];
    __shared__ int cbase[G1];
    __shared__ int wsum[4];
    __shared__ int eb[CCAP];
    __shared__ int dcount[BSZ];
    __shared__ int cur[BSZ];
    int b = blockIdx.x, tid = threadIdx.x;
    int lane = tid & 63, wv = tid >> 6;
    for (int i = tid; i < G1; i += 256) scnt[i] = bh[b * G1 + i];
    if (tid < BSZ) dcount[tid] = 0;
    __syncthreads();
    int v0 = scnt[2 * tid], v1 = scnt[2 * tid + 1];
    int lsum = v0 + v1;
    int pref = lsum;
    for (int o = 1; o < 64; o <<= 1) {
        int t = __shfl_up(pref, o, 64);
        if (lane >= o) pref += t;
    }
    if (lane == 63) wsum[wv] = pref;
    __syncthreads();
    int off = 0;
#pragma unroll
    for (int j = 0; j < 4; ++j) if (j < wv) off += wsum[j];
    int ex = pref - lsum + off;
    cbase[2 * tid] = ex;
    cbase[2 * tid + 1] = ex + v0;
    int tot = wsum[0] + wsum[1] + wsum[2] + wsum[3];
    if (tot > CCAP) tot = CCAP;
    __syncthreads();
#pragma unroll
    for (int cp = 0; cp < 2; ++cp) {     // copy cells 2t, 2t+1 into LDS
        int cell = 2 * tid + cp;
        int c = scnt[cell], lb = cbase[cell];
        int gb = (b * G1 + cell) * CAP;
        if (lb + c > CCAP) c = max(0, CCAP - lb);
        for (int i = 0; i < c; ++i) eb[lb + i] = ebuf[gb + i];
    }
    __syncthreads();
    for (int i = tid; i < tot; i += 256)
        atomicAdd(&dcount[eb[i] >> 14], 1);
    __syncthreads();
    if (tid < 64) {
        int d = (tid < BSZ) ? dcount[tid] : 0;
        int pr = d;
        for (int o = 1; o < 64; o <<= 1) {
            int t = __shfl_up(pr, o, 64);
            if (tid >= o) pr += t;
        }
        if (tid < BSZ) {
            int st = pr - d;
            cur[tid] = b * CCAP + st;
            coff[b * BSZ + tid] = b * CCAP + st;
            deg[b * BSZ + tid] = d;
            dinv[b * BSZ + tid] = rsqrtf((float)d + 1.0f);
        }
    }
    __syncthreads();
    for (int i = tid; i < tot; i += 256) {
        int pk = eb[i];
        int p = atomicAdd(&cur[pk >> 14], 1);
        csrc[p] = (unsigned short)(pk & 16383);
    }
}

// Standalone gemm (layer 2 only): Y(bf16) = (X @ W) * dinv[row].
__global__ __launch_bounds__(256) void k_gemm(const float* __restrict__ X,
                                              const float* __restrict__ W,
                                              const float* __restrict__ dinv,
                                              unsigned short* __restrict__ Y,
                                              int nrows) {
    __shared__ float sX[TKC * 20];
    __shared__ float sW[32 * 132];
    int tid = threadIdx.x;
    int rg = tid & 7;
    int cg = tid >> 3;
    int m0 = blockIdx.x * TMR;
    float acc[2][4] = {{0.f}};
    for (int kc = 0; kc < NF / TKC; ++kc) {
        int k0 = kc * TKC;
        if (tid < 128) {
            int row = tid >> 3, kq = tid & 7;
            int mm = m0 + row; if (mm > nrows - 1) mm = nrows - 1;
            float4 v = *(const float4*)(X + (size_t)mm * NF + k0 + kq * 4);
            sX[(kq * 4 + 0) * 20 + row] = v.x;
            sX[(kq * 4 + 1) * 20 + row] = v.y;
            sX[(kq * 4 + 2) * 20 + row] = v.z;
            sX[(kq * 4 + 3) * 20 + row] = v.w;
        }
#pragma unroll
        for (int j = 0; j < 4; ++j) {
            int idx = tid + 256 * j;
            int k = idx >> 5, cq = idx & 31;
            float4 v = *(const float4*)(W + (size_t)(k0 + k) * NF + cq * 4);
            *(float4*)(sW + cq * 132 + k * 4) = v;
        }
        __syncthreads();
#pragma unroll 8
        for (int k = 0; k < TKC; ++k) {
            float2 xf = *(const float2*)(sX + k * 20 + rg * 2);
            float4 wf = *(const float4*)(sW + cg * 132 + k * 4);
            acc[0][0] = fmaf(xf.x, wf.x, acc[0][0]);
            acc[0][1] = fmaf(xf.x, wf.y, acc[0][1]);
            acc[0][2] = fmaf(xf.x, wf.z, acc[0][2]);
            acc[0][3] = fmaf(xf.x, wf.w, acc[0][3]);
            acc[1][0] = fmaf(xf.y, wf.x, acc[1][0]);
            acc[1][1] = fmaf(xf.y, wf.y, acc[1][1]);
            acc[1][2] = fmaf(xf.y, wf.z, acc[1][2]);
            acc[1][3] = fmaf(xf.y, wf.w, acc[1][3]);
        }
        __syncthreads();
    }
#pragma unroll
    for (int r = 0; r < 2; ++r) {
        int m = m0 + rg * 2 + r;
        if (m < nrows) {
            float ds = dinv[m];
            ushort4 h;
            h.x = f2bf(acc[r][0] * ds);
            h.y = f2bf(acc[r][1] * ds);
            h.z = f2bf(acc[r][2] * ds);
            h.w = f2bf(acc[r][3] * ds);
            *(ushort4*)(Y + (size_t)m * NF + cg * 4) = h;
        }
    }
}

// Gather core, LDS-staged indices (+ per-edge dinv when G rows unscaled).
template <int EDGE_SCALE>
__device__ __forceinline__ void gacc_node(const unsigned short* __restrict__ G,
                                          const unsigned short* __restrict__ csrc,
                                          const float* __restrict__ dv,
                                          unsigned short* ls, float* lsd,
                                          int beg, int end, int q, int f, int lane,
                                          float a[8]) {
    int dg = end - beg;
    int nst = min(dg, MAXD);
    for (int i = lane; i < nst; i += 64) {
        unsigned short s = csrc[beg + i];
        ls[i] = s;
        if (EDGE_SCALE) lsd[i] = dv[s];
    }
    int vi = q;
    int nfull = nst & ~31;
    for (; vi < nfull; vi += 32) {
        int s[8]; float d[8];
#pragma unroll
        for (int j = 0; j < 8; ++j) {
            s[j] = ls[vi + 4 * j];
            d[j] = EDGE_SCALE ? lsd[vi + 4 * j] : 1.f;
        }
        uint4 p[8];
#pragma unroll
        for (int j = 0; j < 8; ++j)
            p[j] = ((const uint4*)(G + (size_t)s[j] * NF))[f];
#pragma unroll
        for (int j = 0; j < 8; ++j) {
            if (EDGE_SCALE) {
                a[0] = fmaf(d[j], bf_lo(p[j].x), a[0]); a[1] = fmaf(d[j], bf_hi(p[j].x), a[1]);
                a[2] = fmaf(d[j], bf_lo(p[j].y), a[2]); a[3] = fmaf(d[j], bf_hi(p[j].y), a[3]);
                a[4] = fmaf(d[j], bf_lo(p[j].z), a[4]); a[5] = fmaf(d[j], bf_hi(p[j].z), a[5]);
                a[6] = fmaf(d[j], bf_lo(p[j].w), a[6]); a[7] = fmaf(d[j], bf_hi(p[j].w), a[7]);
            } else {
                a[0] += bf_lo(p[j].x); a[1] += bf_hi(p[j].x);
                a[2] += bf_lo(p[j].y); a[3] += bf_hi(p[j].y);
                a[4] += bf_lo(p[j].z); a[5] += bf_hi(p[j].z);
                a[6] += bf_lo(p[j].w); a[7] += bf_hi(p[j].w);
            }
        }
    }
    int nfull16 = nst & ~15;
    for (; vi < nfull16; vi += 16) {
        int s[4]; float d[4];
#pragma unroll
        for (int j = 0; j < 4; ++j) {
            s[j] = ls[vi + 4 * j];
            d[j] = EDGE_SCALE ? lsd[vi + 4 * j] : 1.f;
        }
        uint4 p[4];
#pragma unroll
        for (int j = 0; j < 4; ++j)
            p[j] = ((const uint4*)(G + (size_t)s[j] * NF))[f];
#pragma unroll
        for (int j = 0; j < 4; ++j) {
            if (EDGE_SCALE) {
                a[0] = fmaf(d[j], bf_lo(p[j].x), a[0]); a[1] = fmaf(d[j], bf_hi(p[j].x), a[1]);
                a[2] = fmaf(d[j], bf_lo(p[j].y), a[2]); a[3] = fmaf(d[j], bf_hi(p[j].y), a[3]);
                a[4] = fmaf(d[j], bf_lo(p[j].z), a[4]); a[5] = fmaf(d[j], bf_hi(p[j].z), a[5]);
                a[6] = fmaf(d[j], bf_lo(p[j].w), a[6]); a[7] = fmaf(d[j], bf_hi(p[j].w), a[7]);
            } else {
                a[0] += bf_lo(p[j].x); a[1] += bf_hi(p[j].x);
                a[2] += bf_lo(p[j].y); a[3] += bf_hi(p[j].y);
                a[4] += bf_lo(p[j].z); a[5] += bf_hi(p[j].z);
                a[6] += bf_lo(p[j].w); a[7] += bf_hi(p[j].w);
            }
        }
    }
    int npad = (nst + 3) & ~3;
    for (; vi < npad; vi += 4) {         // predicated tail, uniform trips
        int ii = min(vi, nst - 1);
        int s = ls[ii];
        float d = EDGE_SCALE ? lsd[ii] : 1.f;
        uint4 p = ((const uint4*)(G + (size_t)s * NF))[f];
        if (vi < nst) {
            if (EDGE_SCALE) {
                a[0] = fmaf(d, bf_lo(p.x), a[0]); a[1] = fmaf(d, bf_hi(p.x), a[1]);
                a[2] = fmaf(d, bf_lo(p.y), a[2]); a[3] = fmaf(d, bf_hi(p.y), a[3]);
                a[4] = fmaf(d, bf_lo(p.z), a[4]); a[5] = fmaf(d, bf_hi(p.z), a[5]);
                a[6] = fmaf(d, bf_lo(p.w), a[6]); a[7] = fmaf(d, bf_hi(p.w), a[7]);
            } else {
                a[0] += bf_lo(p.x); a[1] += bf_hi(p.x);
                a[2] += bf_lo(p.y); a[3] += bf_hi(p.y);
                a[4] += bf_lo(p.z); a[5] += bf_hi(p.z);
                a[6] += bf_lo(p.w); a[7] += bf_hi(p.w);
            }
        }
    }
    for (int e2 = beg + MAXD + q; e2 < end; e2 += 4) {  // deg>MAXD fallback
        int s = csrc[e2];
        float d = EDGE_SCALE ? dv[s] : 1.f;
        uint4 p = ((const uint4*)(G + (size_t)s * NF))[f];
        if (EDGE_SCALE) {
            a[0] = fmaf(d, bf_lo(p.x), a[0]); a[1] = fmaf(d, bf_hi(p.x), a[1]);
            a[2] = fmaf(d, bf_lo(p.y), a[2]); a[3] = fmaf(d, bf_hi(p.y), a[3]);
            a[4] = fmaf(d, bf_lo(p.z), a[4]); a[5] = fmaf(d, bf_hi(p.z), a[5]);
            a[6] = fmaf(d, bf_lo(p.w), a[6]); a[7] = fmaf(d, bf_hi(p.w), a[7]);
        } else {
            a[0] += bf_lo(p.x); a[1] += bf_hi(p.x);
            a[2] += bf_lo(p.y); a[3] += bf_hi(p.y);
            a[4] += bf_lo(p.z); a[5] += bf_hi(p.z);
            a[6] += bf_lo(p.w); a[7] += bf_hi(p.w);
        }
    }
#pragma unroll
    for (int j = 0; j < 8; ++j) a[j] += __shfl_xor(a[j], 16);
#pragma unroll
    for (int j = 0; j < 8; ++j) a[j] += __shfl_xor(a[j], 32);
}

// Layer-1 gather over UNSCALED h:
// OUT[n] = relu( dinv[n]*( sum_e dinv[s]h[s] + dinv[n]h[n] ) + bias ).
__global__ __launch_bounds__(256, 4) void k_gather(const unsigned short* __restrict__ G,
                                                   const int* __restrict__ off,
                                                   const int* __restrict__ dg,
                                                   const unsigned short* __restrict__ csrc,
                                                   const float* __restrict__ dinv,
                                                   const float* __restrict__ bias,
                                                   float* __restrict__ OUT) {
    __shared__ unsigned short lsbuf[4][MAXD];
    __shared__ float lsdbuf[4][MAXD];
    int wid = threadIdx.x >> 6, lane = threadIdx.x & 63;
    int q = lane >> 4, f = lane & 15;
    int n = blockIdx.x * 4 + wid;
    if (n >= NN) return;
    int beg = off[n], end = beg + dg[n];
    float din = dinv[n];
    float a[8] = {0.f, 0.f, 0.f, 0.f, 0.f, 0.f, 0.f, 0.f};
    gacc_node<1>(G, csrc, dinv, lsbuf[wid], lsdbuf[wid], beg, end, q, f, lane, a);
    if (q == 0) {
        uint4 sp = ((const uint4*)(G + (size_t)n * NF))[f];
        float4 b0 = ((const float4*)bias)[2 * f];
        float4 b1 = ((const float4*)bias)[2 * f + 1];
        float4 o0, o1;
        o0.x = fmaxf(fmaf(din, fmaf(din, bf_lo(sp.x), a[0]), b0.x), 0.f);
        o0.y = fmaxf(fmaf(din, fmaf(din, bf_hi(sp.x), a[1]), b0.y), 0.f);
        o0.z = fmaxf(fmaf(din, fmaf(din, bf_lo(sp.y), a[2]), b0.z), 0.f);
        o0.w = fmaxf(fmaf(din, fmaf(din, bf_hi(sp.y), a[3]), b0.w), 0.f);
        o1.x = fmaxf(fmaf(din, fmaf(din, bf_lo(sp.z), a[4]), b1.x), 0.f);
        o1.y = fmaxf(fmaf(din, fmaf(din, bf_hi(sp.z), a[5]), b1.y), 0.f);
        o1.z = fmaxf(fmaf(din, fmaf(din, bf_lo(sp.w), a[6]), b1.z), 0.f);
        o1.w = fmaxf(fmaf(din, fmaf(din, bf_hi(sp.w), a[7]), b1.w), 0.f);
        ((float4*)(OUT + (size_t)n * NF))[2 * f] = o0;
        ((float4*)(OUT + (size_t)n * NF))[2 * f + 1] = o1;
    }
}

// Layer-2 gather fused with mean-pool + final linear (sliced atomics;
// G rows pre-scaled by gemm2 -> EDGE_SCALE=0).
__global__ __launch_bounds__(256, 4) void k_gatherpool(const unsigned short* __restrict__ G,
                                                       const int* __restrict__ off,
                                                       const int* __restrict__ dg,
                                                       const unsigned short* __restrict__ csrc,
                                                       const float* __restrict__ dinv,
                                                       const float* __restrict__ bias,
                                                       const void* __restrict__ batch,
                                                       const float* __restrict__ Wl,
                                                       const float* __restrict__ cntinv,
                                                       float* __restrict__ outacc) {
    __shared__ float sWl2[8 * NC * 16];  // [j][c][f], conflict-free reads
    __shared__ unsigned short lsbuf[4][MAXD];
    int tid = threadIdx.x;
    for (int i = tid; i < 8 * NC * 16; i += 256) {
        int j = i / (NC * 16);
        int r = i - j * (NC * 16);
        int c = r >> 4, f0 = r & 15;
        sWl2[i] = Wl[(f0 * 8 + j) * NC + c];
    }
    int isb64 = detect64((const int*)batch, NN / 2);
    int wid = tid >> 6, lane = tid & 63;
    int q = lane >> 4, f = lane & 15;
    int n = blockIdx.x * 4 + wid;        // grid is exactly NN/4 -> always valid
    int beg = off[n], end = beg + dg[n];
    float din = dinv[n];
    float a[8] = {0.f, 0.f, 0.f, 0.f, 0.f, 0.f, 0.f, 0.f};
    __syncthreads();                     // sWl2 ready; last block-wide sync
    gacc_node<0>(G, csrc, dinv, lsbuf[wid], (float*)nullptr, beg, end, q, f, lane, a);
    int g = ld_idx(batch, n, isb64);
    uint4 sp = ((const uint4*)(G + (size_t)n * NF))[f];
    float4 b0 = ((const float4*)bias)[2 * f];
    float4 b1 = ((const float4*)bias)[2 * f + 1];
    float h[8];
    h[0] = fmaxf(fmaf(din, a[0] + bf_lo(sp.x), b0.x), 0.f);
    h[1] = fmaxf(fmaf(din, a[1] + bf_hi(sp.x), b0.y), 0.f);
    h[2] = fmaxf(fmaf(din, a[2] + bf_lo(sp.y), b0.z), 0.f);
    h[3] = fmaxf(fmaf(din, a[3] + bf_hi(sp.y), b0.w), 0.f);
    h[4] = fmaxf(fmaf(din, a[4] + bf_lo(sp.z), b1.x), 0.f);
    h[5] = fmaxf(fmaf(din, a[5] + bf_hi(sp.z), b1.y), 0.f);
    h[6] = fmaxf(fmaf(din, a[6] + bf_lo(sp.w), b1.z), 0.f);
    h[7] = fmaxf(fmaf(din, a[7] + bf_hi(sp.w), b1.w), 0.f);
    float p[NC];
#pragma unroll
    for (int c = 0; c < NC; ++c) p[c] = 0.f;
#pragma unroll
    for (int j = 0; j < 8; ++j) {
        const float* wrow = sWl2 + j * (NC * 16) + f;  // [c*16 + f]
#pragma unroll
        for (int c = 0; c < NC; ++c) p[c] = fmaf(h[j], wrow[c * 16], p[c]);
    }
#pragma unroll
    for (int c = 0; c < NC; ++c) {       // reduce over f (bits 0..3)
        p[c] += __shfl_xor(p[c], 1);
        p[c] += __shfl_xor(p[c], 2);
        p[c] += __shfl_xor(p[c], 4);
        p[c] += __shfl_xor(p[c], 8);
    }
    if (lane == 0) {                     // 10 atomics into this block's slice
        float ci = cntinv[g];
        float* dst = outacc + (size_t)(blockIdx.x & (NSL - 1)) * NG * NC + g * NC;
#pragma unroll
        for (int c = 0; c < NC; ++c) atomicAdd(dst + c, p[c] * ci);
    }
}

// Epilogue: out = sum_slices(outacc) + bl (stream-order visibility).
__global__ __launch_bounds__(256) void k_fin(const float* __restrict__ outacc,
                                             const float* __restrict__ bl,
                                             float* __restrict__ out) {
    int tid = threadIdx.x;
    for (int i = tid; i < NG * NC; i += 256) {
        float s = 0.f;
#pragma unroll 8
        for (int sl = 0; sl < NSL; ++sl) s += outacc[(size_t)sl * NG * NC + i];
        out[i] = s + bl[i % NC];
    }
}

extern "C" void kernel_launch(void* const* d_in, const int* in_sizes, int n_in,
                              void* d_out, int out_size, void* d_ws, size_t ws_size,
                              hipStream_t stream) {
    const float* x  = (const float*)d_in[0];
    const void*  ei = d_in[1];
    const void*  bt = d_in[2];
    const float* W1 = (const float*)d_in[3];
    const float* b1 = (const float*)d_in[4];
    const float* W2 = (const float*)d_in[5];
    const float* b2 = (const float*)d_in[6];
    const float* Wl = (const float*)d_in[7];
    const float* bl = (const float*)d_in[8];

    char* ws = (char*)d_ws;
    int*            coff   = (int*)(ws + 0);
    int*            deg    = (int*)(ws + 40000);
    float*          dinv   = (float*)(ws + 80000);
    float*          outacc = (float*)(ws + 120000);   // 64 slices x 640 f32
    float*          cntinv = (float*)(ws + 283840);
    unsigned short* csrc   = (unsigned short*)(ws + 284160);
    int*            bh     = (int*)(ws + 1820160);
    unsigned short* Gb     = (unsigned short*)(ws + 2344448);
    int*            ebuf   = (int*)(ws + 4904448);
    float*          bufB   = (float*)(ws + 4904448); // aliases ebuf (dead after csr)

    k_prepgemm<<<G1 + GEMMB, 256, 0, stream>>>(ei, bt, bh, ebuf, outacc, cntinv,
                                               x, W1, Gb);
    k_csr <<<NB, 256, 0, stream>>>(ebuf, bh, coff, deg, dinv, csrc);

    k_gather<<<(NN + 3) / 4, 256, 0, stream>>>(Gb, coff, deg, csrc, dinv, b1, bufB);
    k_gemm<<<GEMMB, 256, 0, stream>>>(bufB, W2, dinv, Gb, NN);
    k_gatherpool<<<(NN + 3) / 4, 256, 0, stream>>>(Gb, coff, deg, csrc, dinv, b2,
                                                   bt, Wl, cntinv, outacc);
    k_fin<<<1, 256, 0, stream>>>(outacc, bl, (float*)d_out);
}